// Round 12
// baseline (34.573 us; speedup 1.0000x reference)
//
#include <hip/hip_runtime.h>
#include <math.h>

// CropPoolLayer: TF crop_and_resize (bilinear, extrapolation=0) to 14x14
// fused with 2x2 max pool -> [N,7,7,C], NHWC fp32.
// bottom [B=2,H=64,W=64,C=512] fp32, rois [N,5] (bid,x1,y1,x2,y2), im_info[2].
//
// R12 = R9 (64-thr wave, F8 = 2 float4/thread, scalarized geometry, rcp
// normalize, nt stores, XCD swizzle) with the load phase DE-SERIALIZED:
// R9's uniform dedup branches put slot-k loads behind slot-(k-1)'s lerped
// results (copy path), forcing up to 4 dependent memory round-trips per
// wave. R12 issues all 16 F8 corner loads straight-line (address-level
// dedup: duplicate rows/cols load the same address -> same-wave L1 hit, so
// L2-side traffic is unchanged), one waitcnt, then the exact two-stage
// lerp. Identical addresses give identical values -> bit-exact vs copies.

constexpr int POOLSZ = 7;
constexpr int CROPSZ = 14;
constexpr int Hc = 64, Wc = 64, C4 = 128;     // C=512 -> 128 float4 lanes

typedef float vfloat4 __attribute__((ext_vector_type(4)));

struct F8 { float4 lo, hi; };                  // 2 float4 per thread

__device__ __forceinline__ float4 lerp4(float4 a, float4 b, float t) {
    return make_float4(fmaf(b.x - a.x, t, a.x),
                       fmaf(b.y - a.y, t, a.y),
                       fmaf(b.z - a.z, t, a.z),
                       fmaf(b.w - a.w, t, a.w));
}
__device__ __forceinline__ F8 lerp8(const F8& a, const F8& b, float t) {
    F8 r; r.lo = lerp4(a.lo, b.lo, t); r.hi = lerp4(a.hi, b.hi, t); return r;
}
__device__ __forceinline__ float4 f4max(float4 a, float4 b) {
    return make_float4(fmaxf(a.x, b.x), fmaxf(a.y, b.y),
                       fmaxf(a.z, b.z), fmaxf(a.w, b.w));
}
__device__ __forceinline__ F8 f8max(const F8& a, const F8& b) {
    F8 r; r.lo = f4max(a.lo, b.lo); r.hi = f4max(a.hi, b.hi); return r;
}
__device__ __forceinline__ F8 mask8(const F8& v, bool ok) {
    F8 r;
    r.lo = ok ? v.lo : make_float4(0.f, 0.f, 0.f, 0.f);
    r.hi = ok ? v.hi : make_float4(0.f, 0.f, 0.f, 0.f);
    return r;
}
__device__ __forceinline__ int rfl(int x) { return __builtin_amdgcn_readfirstlane(x); }

__global__ __launch_bounds__(64)
void crop_pool_kernel(const float4* __restrict__ bot4,
                      const float* __restrict__ rois,
                      const float* __restrict__ im_info,
                      float4* __restrict__ out4, int nwg)
{
    // bijective XCD swizzle (nwg divisible by 8): same-ROI cells share an XCD L2
    const int bid = blockIdx.x;
    const int blk = (bid & 7) * (nwg >> 3) + (bid >> 3);

    const int n  = blk / (POOLSZ * POOLSZ);
    const int p  = blk - n * (POOLSZ * POOLSZ);
    const int py = p / POOLSZ;
    const int px = p - py * POOLSZ;

    const float inv_w = 1.0f / im_info[1];     // im=1024 (pow2) -> exact
    const float inv_h = 1.0f / im_info[0];
    const float* r5 = rois + n * 5;
    const int bb = rfl((int)r5[0]);
    const float rx1 = r5[1] * inv_w, ry1 = r5[2] * inv_h;
    const float rx2 = r5[3] * inv_w, ry2 = r5[4] * inv_h;

    // TF grid: coord = p1*(D-1) + i * ((p2-p1)*(D-1)/(CROP-1))
    const float sy = (ry2 - ry1) * (float)(Hc - 1) / (float)(CROPSZ - 1);
    const float sx = (rx2 - rx1) * (float)(Wc - 1) / (float)(CROPSZ - 1);
    const float oy = ry1 * (float)(Hc - 1);
    const float ox = rx1 * (float)(Wc - 1);

    // ---- y geometry: 4 row slots (premultiplied, scalarized) ----
    int R0, R1, R2, R3;
    float ly0, ly1; bool vy0, vy1;
    {
        const float ysa = fmaf((float)(2 * py), sy, oy);
        vy0 = (ysa >= 0.f) && (ysa <= (float)(Hc - 1));
        const float fy = floorf(ysa); ly0 = ysa - fy;          // unclipped
        const int y0 = (int)fminf(fmaxf(fy, 0.f), (float)(Hc - 1));
        const int y1 = (int)fminf(fmaxf(ceilf(ysa), 0.f), (float)(Hc - 1));
        R0 = rfl(((bb * Hc + y0) * Wc) * C4);
        R1 = rfl(((bb * Hc + y1) * Wc) * C4);
        const float ysb = fmaf((float)(2 * py + 1), sy, oy);
        vy1 = (ysb >= 0.f) && (ysb <= (float)(Hc - 1));
        const float fy2 = floorf(ysb); ly1 = ysb - fy2;
        const int y2 = (int)fminf(fmaxf(fy2, 0.f), (float)(Hc - 1));
        const int y3 = (int)fminf(fmaxf(ceilf(ysb), 0.f), (float)(Hc - 1));
        R2 = rfl(((bb * Hc + y2) * Wc) * C4);
        R3 = rfl(((bb * Hc + y3) * Wc) * C4);
    }
    // ---- x geometry: 4 corner columns (premultiplied, scalarized) ----
    int cA, cB, cC, cD;
    float lx0, lx1; bool vx0, vx1;
    {
        const float xsa = fmaf((float)(2 * px), sx, ox);
        vx0 = (xsa >= 0.f) && (xsa <= (float)(Wc - 1));
        const float fx = floorf(xsa); lx0 = xsa - fx;          // unclipped
        cA = rfl((int)fminf(fmaxf(fx, 0.f), (float)(Wc - 1)) * C4);
        cB = rfl((int)fminf(fmaxf(ceilf(xsa), 0.f), (float)(Wc - 1)) * C4);
        const float xsb = fmaf((float)(2 * px + 1), sx, ox);
        vx1 = (xsb >= 0.f) && (xsb <= (float)(Wc - 1));
        const float fx2 = floorf(xsb); lx1 = xsb - fx2;
        cC = rfl((int)fminf(fmaxf(fx2, 0.f), (float)(Wc - 1)) * C4);
        cD = rfl((int)fminf(fmaxf(ceilf(xsb), 0.f), (float)(Wc - 1)) * C4);
    }

    const int tid = threadIdx.x;                 // two float4s: tid, tid+64

    // ---- load phase: 16 F8 corner loads, straight-line, no branches ----
    // Duplicate rows/cols produce duplicate addresses; the repeat loads hit
    // the line this wave just fetched (same-CU L1), so L2-side traffic is
    // the dedup'd amount while the wave keeps all 32 loads in flight.
#define LD(dst, base, col)                                                   \
    { dst.lo = bot4[(base) + (col) + tid];                                   \
      dst.hi = bot4[(base) + (col) + tid + 64]; }

    F8 a0, b0, c0, d0, a1, b1, c1, d1;
    F8 a2, b2, c2, d2, a3, b3, c3, d3;
    LD(a0, R0, cA) LD(b0, R0, cB) LD(c0, R0, cC) LD(d0, R0, cD)
    LD(a1, R1, cA) LD(b1, R1, cB) LD(c1, R1, cC) LD(d1, R1, cD)
    LD(a2, R2, cA) LD(b2, R2, cB) LD(c2, R2, cC) LD(d2, R2, cD)
    LD(a3, R3, cA) LD(b3, R3, cB) LD(c3, R3, cC) LD(d3, R3, cD)
#undef LD

    // ---- compute phase: exact two-stage lerp (x then y, reference order) ----
    const F8 X00 = lerp8(a0, b0, lx0);
    const F8 X01 = lerp8(c0, d0, lx1);
    const F8 X10 = lerp8(a1, b1, lx0);
    const F8 X11 = lerp8(c1, d1, lx1);
    const F8 X20 = lerp8(a2, b2, lx0);
    const F8 X21 = lerp8(c2, d2, lx1);
    const F8 X30 = lerp8(a3, b3, lx0);
    const F8 X31 = lerp8(c3, d3, lx1);

    const F8 v00 = lerp8(X00, X10, ly0);
    const F8 v01 = lerp8(X01, X11, ly0);
    const F8 v10 = lerp8(X20, X30, ly1);
    const F8 v11 = lerp8(X21, X31, ly1);

    const F8 acc = f8max(
        f8max(mask8(v00, vy0 && vx0), mask8(v01, vy0 && vx1)),
        f8max(mask8(v10, vy1 && vx0), mask8(v11, vy1 && vx1)));

    // write-once output: nontemporal stores
    const size_t ob = (size_t)blk * C4 + tid;
    vfloat4 s0; s0.x = acc.lo.x; s0.y = acc.lo.y; s0.z = acc.lo.z; s0.w = acc.lo.w;
    vfloat4 s1; s1.x = acc.hi.x; s1.y = acc.hi.y; s1.z = acc.hi.z; s1.w = acc.hi.w;
    __builtin_nontemporal_store(s0, reinterpret_cast<vfloat4*>(&out4[ob]));
    __builtin_nontemporal_store(s1, reinterpret_cast<vfloat4*>(&out4[ob + 64]));
}

extern "C" void kernel_launch(void* const* d_in, const int* in_sizes, int n_in,
                              void* d_out, int out_size, void* d_ws, size_t ws_size,
                              hipStream_t stream) {
    const float4* bottom  = (const float4*)d_in[0];
    const float*  rois    = (const float*)d_in[1];
    const float*  im_info = (const float*)d_in[2];
    float4* out = (float4*)d_out;

    const int N = in_sizes[1] / 5;               // 512 ROIs
    const int nwg = N * POOLSZ * POOLSZ;         // 25088, divisible by 8

    crop_pool_kernel<<<nwg, 64, 0, stream>>>(bottom, rois, im_info, out, nwg);
}

// Round 13
// 29.626 us; speedup vs baseline: 1.1670x; 1.1670x over previous
//
#include <hip/hip_runtime.h>
#include <math.h>

// CropPoolLayer: TF crop_and_resize (bilinear, extrapolation=0) to 14x14
// fused with 2x2 max pool -> [N,7,7,C], NHWC fp32.
// bottom [B=2,H=64,W=64,C=512] fp32, rois [N,5] (bid,x1,y1,x2,y2), im_info[2].
//
// R13 = R9 (best: 29.8us; 64-thr wave, F8 = 2 float4/thread, scalarized
// uniform-branch corner dedup, rcp normalize, nt stores, XCD swizzle) +
// occupancy push: __launch_bounds__(64, 4) caps VGPR at 128 (4 waves/SIMD
// instead of 3 if R9 sat just above the boundary). Live ranges tightened:
// each row slot's corners are lerped immediately and die before the next
// slot's loads (peak ~ 4 corner F8s + accumulated X F8s).
// R12 falsified the "branch serialization" theory (branch conditions are
// scalar and known early; compiler already pipelines the dedup'd loads),
// and confirmed the L1-return-BW term: dedup (~7 vs 16 corners) is worth
// ~12us of L1 traffic -> keep the uniform-branch dedup exactly as R9.

constexpr int POOLSZ = 7;
constexpr int CROPSZ = 14;
constexpr int Hc = 64, Wc = 64, C4 = 128;     // C=512 -> 128 float4 lanes

typedef float vfloat4 __attribute__((ext_vector_type(4)));

struct F8 { float4 lo, hi; };                  // 2 float4 per thread

__device__ __forceinline__ float4 lerp4(float4 a, float4 b, float t) {
    return make_float4(fmaf(b.x - a.x, t, a.x),
                       fmaf(b.y - a.y, t, a.y),
                       fmaf(b.z - a.z, t, a.z),
                       fmaf(b.w - a.w, t, a.w));
}
__device__ __forceinline__ F8 lerp8(const F8& a, const F8& b, float t) {
    F8 r; r.lo = lerp4(a.lo, b.lo, t); r.hi = lerp4(a.hi, b.hi, t); return r;
}
__device__ __forceinline__ float4 f4max(float4 a, float4 b) {
    return make_float4(fmaxf(a.x, b.x), fmaxf(a.y, b.y),
                       fmaxf(a.z, b.z), fmaxf(a.w, b.w));
}
__device__ __forceinline__ F8 f8max(const F8& a, const F8& b) {
    F8 r; r.lo = f4max(a.lo, b.lo); r.hi = f4max(a.hi, b.hi); return r;
}
__device__ __forceinline__ F8 mask8(const F8& v, bool ok) {
    F8 r;
    r.lo = ok ? v.lo : make_float4(0.f, 0.f, 0.f, 0.f);
    r.hi = ok ? v.hi : make_float4(0.f, 0.f, 0.f, 0.f);
    return r;
}
__device__ __forceinline__ int rfl(int x) { return __builtin_amdgcn_readfirstlane(x); }

__global__ __launch_bounds__(64, 4)            // cap VGPR at 128 -> 4 waves/SIMD
void crop_pool_kernel(const float4* __restrict__ bot4,
                      const float* __restrict__ rois,
                      const float* __restrict__ im_info,
                      float4* __restrict__ out4, int nwg)
{
    // bijective XCD swizzle (nwg divisible by 8): same-ROI cells share an XCD L2
    const int bid = blockIdx.x;
    const int blk = (bid & 7) * (nwg >> 3) + (bid >> 3);

    const int n  = blk / (POOLSZ * POOLSZ);
    const int p  = blk - n * (POOLSZ * POOLSZ);
    const int py = p / POOLSZ;
    const int px = p - py * POOLSZ;

    const float inv_w = 1.0f / im_info[1];     // im=1024 (pow2) -> exact
    const float inv_h = 1.0f / im_info[0];
    const float* r5 = rois + n * 5;
    const int bb = rfl((int)r5[0]);
    const float rx1 = r5[1] * inv_w, ry1 = r5[2] * inv_h;
    const float rx2 = r5[3] * inv_w, ry2 = r5[4] * inv_h;

    // TF grid: coord = p1*(D-1) + i * ((p2-p1)*(D-1)/(CROP-1))
    const float sy = (ry2 - ry1) * (float)(Hc - 1) / (float)(CROPSZ - 1);
    const float sx = (rx2 - rx1) * (float)(Wc - 1) / (float)(CROPSZ - 1);
    const float oy = ry1 * (float)(Hc - 1);
    const float ox = rx1 * (float)(Wc - 1);

    // ---- y geometry: 4 row slots (premultiplied, scalarized) ----
    int R0, R1, R2, R3;
    float ly0, ly1; bool vy0, vy1;
    {
        const float ysa = fmaf((float)(2 * py), sy, oy);
        vy0 = (ysa >= 0.f) && (ysa <= (float)(Hc - 1));
        const float fy = floorf(ysa); ly0 = ysa - fy;          // unclipped
        const int y0 = (int)fminf(fmaxf(fy, 0.f), (float)(Hc - 1));
        const int y1 = (int)fminf(fmaxf(ceilf(ysa), 0.f), (float)(Hc - 1));
        R0 = rfl(((bb * Hc + y0) * Wc) * C4);
        R1 = rfl(((bb * Hc + y1) * Wc) * C4);
        const float ysb = fmaf((float)(2 * py + 1), sy, oy);
        vy1 = (ysb >= 0.f) && (ysb <= (float)(Hc - 1));
        const float fy2 = floorf(ysb); ly1 = ysb - fy2;
        const int y2 = (int)fminf(fmaxf(fy2, 0.f), (float)(Hc - 1));
        const int y3 = (int)fminf(fmaxf(ceilf(ysb), 0.f), (float)(Hc - 1));
        R2 = rfl(((bb * Hc + y2) * Wc) * C4);
        R3 = rfl(((bb * Hc + y3) * Wc) * C4);
    }
    // ---- x geometry: 4 corner columns (premultiplied, scalarized) ----
    int cA, cB, cC, cD;
    float lx0, lx1; bool vx0, vx1;
    {
        const float xsa = fmaf((float)(2 * px), sx, ox);
        vx0 = (xsa >= 0.f) && (xsa <= (float)(Wc - 1));
        const float fx = floorf(xsa); lx0 = xsa - fx;          // unclipped
        cA = rfl((int)fminf(fmaxf(fx, 0.f), (float)(Wc - 1)) * C4);
        cB = rfl((int)fminf(fmaxf(ceilf(xsa), 0.f), (float)(Wc - 1)) * C4);
        const float xsb = fmaf((float)(2 * px + 1), sx, ox);
        vx1 = (xsb >= 0.f) && (xsb <= (float)(Wc - 1));
        const float fx2 = floorf(xsb); lx1 = xsb - fx2;
        cC = rfl((int)fminf(fmaxf(fx2, 0.f), (float)(Wc - 1)) * C4);
        cD = rfl((int)fminf(fmaxf(ceilf(xsb), 0.f), (float)(Wc - 1)) * C4);
    }

    const int tid = threadIdx.x;                 // two float4s: tid, tid+64

    // X[slot][s]: x-lerped values; corners are lerped per slot and die
    // before the next slot's loads (keeps peak VGPR under the 128 cap).
    F8 X00, X01, X10, X11, X20, X21, X30, X31;

    // Load + x-lerp one row slot with column dedup. SGPR indices ->
    // s_cmp/s_cbranch uniform branches; skipped loads never issued.
    auto fresh = [&](int rb, F8& Xs0, F8& Xs1) {
        F8 a, b, c, d;
        a.lo = bot4[rb + cA + tid]; a.hi = bot4[rb + cA + tid + 64];
        if (cB != cA) { b.lo = bot4[rb + cB + tid]; b.hi = bot4[rb + cB + tid + 64]; }
        else b = a;
        if (cC == cA) c = a; else if (cC == cB) c = b;
        else { c.lo = bot4[rb + cC + tid]; c.hi = bot4[rb + cC + tid + 64]; }
        if (cD == cC) d = c; else if (cD == cB) d = b;
        else { d.lo = bot4[rb + cD + tid]; d.hi = bot4[rb + cD + tid + 64]; }
        Xs0 = lerp8(a, b, lx0);
        Xs1 = lerp8(c, d, lx1);
    };

    fresh(R0, X00, X01);
    if (R1 == R0)      { X10 = X00; X11 = X01; }
    else                 fresh(R1, X10, X11);
    if (R2 == R0)      { X20 = X00; X21 = X01; }
    else if (R2 == R1) { X20 = X10; X21 = X11; }
    else                 fresh(R2, X20, X21);
    if (R3 == R2)      { X30 = X20; X31 = X21; }
    else if (R3 == R1) { X30 = X10; X31 = X11; }
    else                 fresh(R3, X30, X31);

    // y-lerp (reference order: top + (bot-top)*ly), mask invalid samples to 0
    const F8 v00 = lerp8(X00, X10, ly0);
    const F8 v01 = lerp8(X01, X11, ly0);
    const F8 v10 = lerp8(X20, X30, ly1);
    const F8 v11 = lerp8(X21, X31, ly1);

    const F8 acc = f8max(
        f8max(mask8(v00, vy0 && vx0), mask8(v01, vy0 && vx1)),
        f8max(mask8(v10, vy1 && vx0), mask8(v11, vy1 && vx1)));

    // write-once output: nontemporal stores
    const size_t ob = (size_t)blk * C4 + tid;
    vfloat4 s0; s0.x = acc.lo.x; s0.y = acc.lo.y; s0.z = acc.lo.z; s0.w = acc.lo.w;
    vfloat4 s1; s1.x = acc.hi.x; s1.y = acc.hi.y; s1.z = acc.hi.z; s1.w = acc.hi.w;
    __builtin_nontemporal_store(s0, reinterpret_cast<vfloat4*>(&out4[ob]));
    __builtin_nontemporal_store(s1, reinterpret_cast<vfloat4*>(&out4[ob + 64]));
}

extern "C" void kernel_launch(void* const* d_in, const int* in_sizes, int n_in,
                              void* d_out, int out_size, void* d_ws, size_t ws_size,
                              hipStream_t stream) {
    const float4* bottom  = (const float4*)d_in[0];
    const float*  rois    = (const float*)d_in[1];
    const float*  im_info = (const float*)d_in[2];
    float4* out = (float4*)d_out;

    const int N = in_sizes[1] / 5;               // 512 ROIs
    const int nwg = N * POOLSZ * POOLSZ;         // 25088, divisible by 8

    crop_pool_kernel<<<nwg, 64, 0, stream>>>(bottom, rois, im_info, out, nwg);
}